// Round 1
// baseline (1206.970 us; speedup 1.0000x reference)
//
#include <hip/hip_runtime.h>

typedef _Float16 half_t;
typedef _Float16 half8 __attribute__((ext_vector_type(8)));
typedef float float4v __attribute__((ext_vector_type(4)));

constexpr int NB = 8, NC = 256, NH = 128, NW = 128;
constexpr int CORR_PAD = 96;  // 81 corr channels zero-padded to 96 (3 ci-chunks of 32 / 6 of 16)

// ---------------------------------------------------------------------------
// Weight prep: transpose conv weights to k-contiguous fp16 layouts.
// Wt1: [64][968]  k = chunk*160 + kk*32 + u*16 + cil ; kykx = kk*2+u (9=dummy->0) ; ci = chunk*16+cil (>=81 -> 0)
// Wt2: [64][648]  same with 4 chunks (ci < 64)
// W3t: [2][576]   k = kykx*64 + ci
// ---------------------------------------------------------------------------
__global__ void prep_weights_kernel(const float* __restrict__ w1,
                                    const float* __restrict__ w2,
                                    const float* __restrict__ w3,
                                    half_t* __restrict__ Wt1,
                                    half_t* __restrict__ Wt2,
                                    half_t* __restrict__ W3t) {
  int stride = gridDim.x * blockDim.x;
  int idx0 = blockIdx.x * blockDim.x + threadIdx.x;
  for (int i = idx0; i < 64 * 968; i += stride) {
    int co = i / 968, k = i % 968;
    float v = 0.f;
    if (k < 960) {
      int chunk = k / 160, rem = k % 160;
      int kk = rem / 32, r2 = rem % 32;
      int u = r2 / 16, cil = r2 % 16;
      int kykx = kk * 2 + u, ci = chunk * 16 + cil;
      if (kykx < 9 && ci < 81) {
        int ky = kykx / 3, kx = kykx % 3;
        v = w1[((co * 81 + ci) * 3 + ky) * 3 + kx];
      }
    }
    Wt1[i] = (half_t)v;
  }
  for (int i = idx0; i < 64 * 648; i += stride) {
    int co = i / 648, k = i % 648;
    float v = 0.f;
    if (k < 640) {
      int chunk = k / 160, rem = k % 160;
      int kk = rem / 32, r2 = rem % 32;
      int u = r2 / 16, cil = r2 % 16;
      int kykx = kk * 2 + u, ci = chunk * 16 + cil;
      if (kykx < 9 && ci < 64) {
        int ky = kykx / 3, kx = kykx % 3;
        v = w2[((co * 64 + ci) * 3 + ky) * 3 + kx];
      }
    }
    Wt2[i] = (half_t)v;
  }
  for (int i = idx0; i < 2 * 576; i += stride) {
    int co = i / 576, k = i % 576;
    int kykx = k / 64, ci = k % 64;
    int ky = kykx / 3, kx = kykx % 3;
    W3t[i] = (half_t)w3[((co * 64 + ci) * 3 + ky) * 3 + kx];
  }
}

// ---------------------------------------------------------------------------
// Correlation: corr[b][y][x][k=(dy+4)*9+(dx+4)] = (1/16) * sum_c F1[b,c,y,x]*F2[b,c,(y-dy)%H,(x-dx)%W]
// Block: 576 thr = 9 waves (wave = dyi), full-width 128x4 strip. fp32 math, fp16 output (NHWC, 96-pad).
// LDS swizzle: byte ^= ((x>>3)&7)<<4 breaks the stride-8-column bank collision (b128 stays 16B-aligned).
// ---------------------------------------------------------------------------
__global__ __launch_bounds__(576) void corr_kernel(const float* __restrict__ F1,
                                                   const float* __restrict__ F2,
                                                   half_t* __restrict__ corr) {
  __shared__ __align__(16) float F1L[4 * 128 * 8];   // [r][x][c] swizzled, 16 KB
  __shared__ __align__(16) float F2L[12 * 128 * 8];  // [rr][x][c] swizzled, 48 KB

  int bid = blockIdx.x;
  int b = bid & 7, strip = bid >> 3;  // b = bid%8 -> one batch per XCD (L2 halo reuse)
  int y0 = strip * 4;

  int tid = threadIdx.x;
  int dyi = tid >> 6;        // 0..8  (dy = dyi-4)
  int lane = tid & 63;
  int r = lane >> 4;         // row in strip 0..3
  int x0 = (lane & 15) * 8;  // 8-pixel group

  int frow = r + 8 - dyi;  // F2L row index (0..11)

  float acc[9][8];
#pragma unroll
  for (int i = 0; i < 9; ++i)
#pragma unroll
    for (int j = 0; j < 8; ++j) acc[i][j] = 0.f;

  const float* F1b = F1 + (size_t)b * NC * NH * NW;
  const float* F2b = F2 + (size_t)b * NC * NH * NW;

  for (int c0 = 0; c0 < NC; c0 += 8) {
    __syncthreads();
    // stage 8 channels: F1 rows y0..y0+3, F2 rows (y0-4..y0+7) mod 128 (torus)
    for (int s = tid; s < 2048; s += 576) {
      int isF2 = (s >= 512);
      int s2 = isF2 ? s - 512 : s;
      int rr = s2 >> 7, xx = s2 & 127;
      const float* src;
      float* dstl;
      if (!isF2) {
        src = F1b + (size_t)c0 * NH * NW + (size_t)(y0 + rr) * NW + xx;
        dstl = F1L;
      } else {
        int yy = (y0 - 4 + rr) & 127;
        src = F2b + (size_t)c0 * NH * NW + (size_t)yy * NW + xx;
        dstl = F2L;
      }
      int swz = ((xx >> 3) & 7) << 4;
#pragma unroll
      for (int c = 0; c < 8; ++c) {
        float v = src[(size_t)c * NH * NW];
        int byt = (((rr * 128 + xx) * 8 + c) * 4) ^ swz;
        *(float*)((char*)dstl + byt) = v;
      }
    }
    __syncthreads();
#pragma unroll
    for (int sub = 0; sub < 2; ++sub) {  // 4-channel halves of the 8-chunk
#pragma unroll
      for (int ph = 0; ph < 2; ++ph) {  // 4-pixel halves (register pressure)
        float4v f1v[4];
#pragma unroll
        for (int p = 0; p < 4; ++p) {
          int xx = x0 + ph * 4 + p;
          int byt = (((r * 128 + xx) * 8 + sub * 4) * 4) ^ (((xx >> 3) & 7) << 4);
          f1v[p] = *(float4v*)((char*)F1L + byt);
        }
        float4v f2v[12];
#pragma unroll
        for (int s = 0; s < 12; ++s) {
          int xx = (x0 + ph * 4 + s - 4) & 127;
          int byt = (((frow * 128 + xx) * 8 + sub * 4) * 4) ^ (((xx >> 3) & 7) << 4);
          f2v[s] = *(float4v*)((char*)F2L + byt);
        }
#pragma unroll
        for (int dxi = 0; dxi < 9; ++dxi) {
#pragma unroll
          for (int p = 0; p < 4; ++p) {
            float4v a = f1v[p];
            float4v bb = f2v[p + 8 - dxi];  // col = (x - (dxi-4)) & 127
            float t = acc[dxi][ph * 4 + p];
            t = __builtin_fmaf(a[0], bb[0], t);
            t = __builtin_fmaf(a[1], bb[1], t);
            t = __builtin_fmaf(a[2], bb[2], t);
            t = __builtin_fmaf(a[3], bb[3], t);
            acc[dxi][ph * 4 + p] = t;
          }
        }
      }
    }
  }

  half_t* dst = corr + ((size_t)b * NH * NW + (size_t)(y0 + r) * NW) * CORR_PAD;
#pragma unroll
  for (int p = 0; p < 8; ++p) {
    int x = x0 + p;
#pragma unroll
    for (int dxi = 0; dxi < 9; ++dxi)
      dst[(size_t)x * CORR_PAD + dyi * 9 + dxi] = (half_t)(acc[dxi][p] * 0.0625f);
  }
}

// ---------------------------------------------------------------------------
// Conv 3x3 (SAME, zero pad) as implicit GEMM on mfma_f32_16x16x32_f16.
// M=64 co, N=512 px (4-row strip, 8 waves x 64px), K = NCHUNK*160 (kykx padded 9->10, zero weights).
// A (weights) in LDS [64][KPAD]; B built from NHWC fp16 input tile [6][130][24] in LDS.
// ---------------------------------------------------------------------------
template <int CIN_PAD, int NCHUNK, int KPAD, bool RELU>
__global__ __launch_bounds__(512) void conv_kernel(const half_t* __restrict__ src,
                                                   const half_t* __restrict__ Wt,
                                                   const float* __restrict__ bias,
                                                   half_t* __restrict__ dst) {
  __shared__ __align__(16) half_t Alds[64 * KPAD];
  __shared__ __align__(16) half_t Btile[6 * 130 * 24];

  int bid = blockIdx.x;
  int b = bid & 7, strip = bid >> 3;
  int y0 = strip * 4;
  int tid = threadIdx.x;

  for (int i = tid * 8; i < 64 * KPAD; i += 512 * 8)
    *(half8*)(Alds + i) = *(const half8*)(Wt + i);

  int wave = tid >> 6, lane = tid & 63;
  int row = wave >> 1;        // 0..3 : y = y0+row
  int xh = (wave & 1) * 64;   // x half
  int l15 = lane & 15, q = lane >> 4;

  float4v acc[4][4];
#pragma unroll
  for (int i = 0; i < 4; ++i)
#pragma unroll
    for (int j = 0; j < 4; ++j)
#pragma unroll
      for (int e = 0; e < 4; ++e) acc[i][j][e] = 0.f;

  const half_t* srcb = src + (size_t)b * NH * NW * CIN_PAD;

  for (int chunk = 0; chunk < NCHUNK; ++chunk) {
    __syncthreads();
    // stage B tile: rows y0-1..y0+4, cols -1..128, 16 ci of this chunk (zero-padded borders)
    for (int s = tid; s < 1560; s += 512) {
      int sub = (s >= 780) ? 1 : 0;
      int s2 = s - sub * 780;
      int trow = s2 / 130, tcol = s2 % 130;
      int yy = y0 - 1 + trow, xx = tcol - 1;
      half8 v;
#pragma unroll
      for (int e = 0; e < 8; ++e) v[e] = (half_t)0.f;
      if (yy >= 0 && yy < NH && xx >= 0 && xx < NW)
        v = *(const half8*)(srcb + ((size_t)yy * NW + xx) * CIN_PAD + chunk * 16 + sub * 8);
      *(half8*)(Btile + ((size_t)trow * 130 + tcol) * 24 + sub * 8) = v;
    }
    __syncthreads();
#pragma unroll
    for (int kk = 0; kk < 5; ++kk) {  // K-step of 32 = 2 kykx x 16 ci
      half8 a[4];
#pragma unroll
      for (int mf = 0; mf < 4; ++mf)
        a[mf] = *(const half8*)(Alds + (size_t)(mf * 16 + l15) * KPAD + chunk * 160 + kk * 32 + q * 8);
      int u = q >> 1, cil8 = (q & 1) * 8;
      int kykx = kk * 2 + u;
      int dy = 0, dx = 0;
      if (kykx < 9) { dy = kykx / 3 - 1; dx = kykx % 3 - 1; }  // dummy kykx=9: zero weights
      int trow = row + 1 + dy;
      half8 bf[4];
#pragma unroll
      for (int nf = 0; nf < 4; ++nf) {
        int tcol = 1 + xh + nf * 16 + l15 + dx;
        bf[nf] = *(const half8*)(Btile + ((size_t)trow * 130 + tcol) * 24 + cil8);
      }
#pragma unroll
      for (int mf = 0; mf < 4; ++mf)
#pragma unroll
        for (int nf = 0; nf < 4; ++nf)
          acc[mf][nf] = __builtin_amdgcn_mfma_f32_16x16x32_f16(a[mf], bf[nf], acc[mf][nf], 0, 0, 0);
    }
  }

  // epilogue: D layout col=l15 (px), row=q*4+e (co). +bias, ReLU, fp16 NHWC store
  int y = y0 + row;
  half_t* dstb = dst + ((size_t)b * NH * NW + (size_t)y * NW) * 64;
#pragma unroll
  for (int mf = 0; mf < 4; ++mf) {
    int cobase = mf * 16 + q * 4;
    float4v bv = *(const float4v*)(bias + cobase);
#pragma unroll
    for (int nf = 0; nf < 4; ++nf) {
      int x = xh + nf * 16 + l15;
      union { half_t h[4]; unsigned long long u64; } pk;
#pragma unroll
      for (int e = 0; e < 4; ++e) {
        float v = acc[mf][nf][e] + bv[e];
        if (RELU) v = v > 0.f ? v : 0.f;
        pk.h[e] = (half_t)v;
      }
      *(unsigned long long*)(dstb + (size_t)x * 64 + cobase) = pk.u64;
    }
  }
}

// ---------------------------------------------------------------------------
// Conv3: 64 -> 2, fp32 accumulate, NCHW fp32 output (the final flow)
// ---------------------------------------------------------------------------
__global__ __launch_bounds__(256) void conv3_kernel(const half_t* __restrict__ h2,
                                                    const half_t* __restrict__ W3t,
                                                    const float* __restrict__ b3,
                                                    float* __restrict__ out) {
  __shared__ __align__(16) half_t w[2 * 576];
  int tid = threadIdx.x;
  for (int i = tid * 8; i < 1152; i += 256 * 8) *(half8*)(w + i) = *(const half8*)(W3t + i);
  __syncthreads();
  int p = blockIdx.x * 256 + tid;
  int b = p >> 14, y = (p >> 7) & 127, x = p & 127;
  const half_t* hb = h2 + (size_t)b * NH * NW * 64;
  float a0 = 0.f, a1 = 0.f;
#pragma unroll
  for (int kykx = 0; kykx < 9; ++kykx) {
    int yy = y + kykx / 3 - 1, xx = x + kykx % 3 - 1;
    if (yy < 0 || yy >= NH || xx < 0 || xx >= NW) continue;
    const half_t* sp = hb + ((size_t)yy * NW + xx) * 64;
#pragma unroll
    for (int c8 = 0; c8 < 8; ++c8) {
      half8 v = *(const half8*)(sp + c8 * 8);
      half8 w0 = *(const half8*)(w + kykx * 64 + c8 * 8);
      half8 w1 = *(const half8*)(w + 576 + kykx * 64 + c8 * 8);
#pragma unroll
      for (int j = 0; j < 8; ++j) {
        a0 = __builtin_fmaf((float)v[j], (float)w0[j], a0);
        a1 = __builtin_fmaf((float)v[j], (float)w1[j], a1);
      }
    }
  }
  out[((size_t)b * 2 + 0) * NH * NW + (size_t)y * NW + x] = a0 + b3[0];
  out[((size_t)b * 2 + 1) * NH * NW + (size_t)y * NW + x] = a1 + b3[1];
}

// ---------------------------------------------------------------------------
extern "C" void kernel_launch(void* const* d_in, const int* in_sizes, int n_in,
                              void* d_out, int out_size, void* d_ws, size_t ws_size,
                              hipStream_t stream) {
  const float* F1 = (const float*)d_in[0];
  const float* F2 = (const float*)d_in[1];
  const float* w1 = (const float*)d_in[2];
  const float* b1 = (const float*)d_in[3];
  const float* w2 = (const float*)d_in[4];
  const float* b2 = (const float*)d_in[5];
  const float* w3 = (const float*)d_in[6];
  const float* b3 = (const float*)d_in[7];
  float* out = (float*)d_out;

  char* ws = (char*)d_ws;
  const size_t corr_bytes = (size_t)NB * NH * NW * CORR_PAD * 2;  // 25165824
  const size_t h_bytes = (size_t)NB * NH * NW * 64 * 2;           // 16777216
  const size_t h1_off = corr_bytes;
  const size_t h2_off = h1_off + h_bytes;
  const size_t wt1_off = h2_off + h_bytes;
  const size_t wt2_off = wt1_off + (size_t)64 * 968 * 2;
  const size_t w3t_off = wt2_off + (size_t)64 * 648 * 2;

  half_t* corr = (half_t*)(ws);
  half_t* h1 = (half_t*)(ws + h1_off);
  half_t* h2 = (half_t*)(ws + h2_off);
  half_t* Wt1 = (half_t*)(ws + wt1_off);
  half_t* Wt2 = (half_t*)(ws + wt2_off);
  half_t* W3t = (half_t*)(ws + w3t_off);

  hipMemsetAsync(corr, 0, corr_bytes, stream);  // zeros the 81..95 ci pad (re-poisoned each launch)
  prep_weights_kernel<<<128, 256, 0, stream>>>(w1, w2, w3, Wt1, Wt2, W3t);
  corr_kernel<<<256, 576, 0, stream>>>(F1, F2, corr);
  conv_kernel<96, 6, 968, true><<<256, 512, 0, stream>>>(corr, Wt1, b1, h1);
  conv_kernel<64, 4, 648, true><<<256, 512, 0, stream>>>(h1, Wt2, b2, h2);
  conv3_kernel<<<512, 256, 0, stream>>>(h2, W3t, b3, out);
}

// Round 2
// 571.747 us; speedup vs baseline: 2.1110x; 2.1110x over previous
//
#include <hip/hip_runtime.h>

typedef _Float16 half_t;
typedef _Float16 half8 __attribute__((ext_vector_type(8)));
typedef float float4v __attribute__((ext_vector_type(4)));

constexpr int NB = 8, NC = 256, NH = 128, NW = 128;
constexpr int CORR_PAD = 96;  // 81 corr channels zero-padded to 96

// ---------------------------------------------------------------------------
// Weight prep: transpose conv weights to k-contiguous fp16 layouts.
// Wt1: [64][968]  k = chunk*160 + kk*32 + u*16 + cil ; kykx = kk*2+u (9=dummy->0) ; ci = chunk*16+cil (>=81 -> 0)
// Wt2: [64][648]  same with 4 chunks (ci < 64)
// W3t: [2][576]   k = kykx*64 + ci
// ---------------------------------------------------------------------------
__global__ void prep_weights_kernel(const float* __restrict__ w1,
                                    const float* __restrict__ w2,
                                    const float* __restrict__ w3,
                                    half_t* __restrict__ Wt1,
                                    half_t* __restrict__ Wt2,
                                    half_t* __restrict__ W3t) {
  int stride = gridDim.x * blockDim.x;
  int idx0 = blockIdx.x * blockDim.x + threadIdx.x;
  for (int i = idx0; i < 64 * 968; i += stride) {
    int co = i / 968, k = i % 968;
    float v = 0.f;
    if (k < 960) {
      int chunk = k / 160, rem = k % 160;
      int kk = rem / 32, r2 = rem % 32;
      int u = r2 / 16, cil = r2 % 16;
      int kykx = kk * 2 + u, ci = chunk * 16 + cil;
      if (kykx < 9 && ci < 81) {
        int ky = kykx / 3, kx = kykx % 3;
        v = w1[((co * 81 + ci) * 3 + ky) * 3 + kx];
      }
    }
    Wt1[i] = (half_t)v;
  }
  for (int i = idx0; i < 64 * 648; i += stride) {
    int co = i / 648, k = i % 648;
    float v = 0.f;
    if (k < 640) {
      int chunk = k / 160, rem = k % 160;
      int kk = rem / 32, r2 = rem % 32;
      int u = r2 / 16, cil = r2 % 16;
      int kykx = kk * 2 + u, ci = chunk * 16 + cil;
      if (kykx < 9 && ci < 64) {
        int ky = kykx / 3, kx = kykx % 3;
        v = w2[((co * 64 + ci) * 3 + ky) * 3 + kx];
      }
    }
    Wt2[i] = (half_t)v;
  }
  for (int i = idx0; i < 2 * 576; i += stride) {
    int co = i / 576, k = i % 576;
    int kykx = k / 64, ci = k % 64;
    int ky = kykx / 3, kx = kykx % 3;
    W3t[i] = (half_t)w3[((co * 64 + ci) * 3 + ky) * 3 + kx];
  }
}

// ---------------------------------------------------------------------------
// Correlation via MFMA band trick.
// corr(dyi,dxi)[y,x] = (1/16) sum_c F1[y,x,c] * F2[(y+4-dyi)&127, (x+4-dxi)&127, c]
// Block = 1 output row y, 8 waves; wave w owns 16-px group x0w=16w.
// Per (chunk of 32ch, dyi): D = mfma(A=F2window_frag, B=F1_frag):
//   D[m=q*4+e][n=l15]: n -> pixel x0w+l15, m -> window position.
//   W1: F2 x = x0w-4+m  -> dxi = l15+8-4q-e ; W2: F2 x = x0w+12+m -> dxi = l15-8-4q-e.
// LDS: rows r=0..8 = F2 global rows (y-4+r)&127 (dyi = 8-r), slot 9 = F1 row y.
// fp16 [row][x][32ch], XOR swizzle byte ^= ((x&7)<<4) on both write (b64) and read (b128).
// ---------------------------------------------------------------------------
__global__ __launch_bounds__(512, 4) void corr_kernel(const float* __restrict__ F1,
                                                      const float* __restrict__ F2,
                                                      half_t* __restrict__ corr) {
  __shared__ __align__(16) half_t L[10 * 128 * 32];  // 80 KB

  int bid = blockIdx.x;
  int b = bid & 7, y = bid >> 3;  // batch -> XCD pinning
  int tid = threadIdx.x;
  int wave = tid >> 6, lane = tid & 63;
  int q = lane >> 4, l15 = lane & 15;
  int x0w = wave * 16;

  const float* F1b = F1 + (size_t)b * (NC * NH * NW);
  const float* F2b = F2 + (size_t)b * (NC * NH * NW);

  float4v acc[9][2];
#pragma unroll
  for (int i = 0; i < 9; ++i)
#pragma unroll
    for (int j = 0; j < 2; ++j)
#pragma unroll
      for (int e = 0; e < 4; ++e) acc[i][j][e] = 0.f;

  // lane-invariant fragment byte addresses (within a row slot)
  int xB = x0w + l15;                                        // F1 pixel
  int bfAddr = 9 * 8192 + ((xB * 64 + q * 16) ^ ((xB & 7) << 4));
  int x1 = (x0w - 4 + l15) & 127;                            // W1 window pos
  int x2 = (x0w + 12 + l15) & 127;                           // W2 window pos
  int a1Off = (x1 * 64 + q * 16) ^ ((x1 & 7) << 4);
  int a2Off = (x2 * 64 + q * 16) ^ ((x2 & 7) << 4);

  // staging constants: thread's x is fixed (512 % 128 == 0)
  int sx = tid & 127;
  int swzW = ((sx & 7) << 4);
  int rc0 = tid >> 7;  // 0..3

  for (int c0 = 0; c0 < NC; c0 += 32) {
    __syncthreads();
    // stage 10 rows x 128 x x 8 ch-groups(4ch): 20 units/thread
    for (int it = 0; it < 20; ++it) {
      int rc = rc0 + it * 4;
      int cg = rc & 7, r = rc >> 3;  // r in [0,9]
      int gy = (r == 9) ? y : ((y - 4 + r) & 127);
      const float* sp = (r == 9 ? F1b : F2b) + (size_t)(c0 + cg * 4) * (NH * NW) + gy * NW + sx;
      float v0 = sp[0];
      float v1 = sp[NH * NW];
      float v2 = sp[2 * NH * NW];
      float v3 = sp[3 * NH * NW];
      union { half_t h[4]; unsigned long long u; } pk;
      pk.h[0] = (half_t)v0; pk.h[1] = (half_t)v1; pk.h[2] = (half_t)v2; pk.h[3] = (half_t)v3;
      int byt = r * 8192 + ((sx * 64 + cg * 8) ^ swzW);
      *(unsigned long long*)((char*)L + byt) = pk.u;
    }
    __syncthreads();

    half8 bf = *(const half8*)((const char*)L + bfAddr);  // F1 frag, reused over dy
#pragma unroll
    for (int dyi = 0; dyi < 9; ++dyi) {
      int rbase = (8 - dyi) * 8192;
      half8 a1 = *(const half8*)((const char*)L + rbase + a1Off);
      half8 a2 = *(const half8*)((const char*)L + rbase + a2Off);
      acc[dyi][0] = __builtin_amdgcn_mfma_f32_16x16x32_f16(a1, bf, acc[dyi][0], 0, 0, 0);
      acc[dyi][1] = __builtin_amdgcn_mfma_f32_16x16x32_f16(a2, bf, acc[dyi][1], 0, 0, 0);
    }
  }

  // store: lane's pixel is xB; element e of window w has dxi = top - e
  half_t* pbase = corr + ((size_t)b * (NH * NW) + (size_t)y * NW + xB) * CORR_PAD;
  int top1 = l15 + 8 - 4 * q;
  int top2 = l15 - 8 - 4 * q;
#pragma unroll
  for (int dyi = 0; dyi < 9; ++dyi) {
#pragma unroll
    for (int e = 0; e < 4; ++e) {
      int d1 = top1 - e;
      if (d1 >= 0 && d1 <= 8) pbase[dyi * 9 + d1] = (half_t)(acc[dyi][0][e] * 0.0625f);
      int d2 = top2 - e;
      if (d2 >= 0 && d2 <= 8) pbase[dyi * 9 + d2] = (half_t)(acc[dyi][1][e] * 0.0625f);
    }
  }
}

// ---------------------------------------------------------------------------
// Conv 3x3 (SAME) implicit GEMM, mfma_f32_16x16x32_f16.
// Chunked A staging: only the current 160-K slice of weights in LDS (21.5 KB)
// + B tile (37.4 KB) -> 59 KB -> 2 blocks/CU.
// ---------------------------------------------------------------------------
template <int CIN_PAD, int NCHUNK, bool RELU>
__global__ __launch_bounds__(512, 4) void conv_kernel(const half_t* __restrict__ src,
                                                      const half_t* __restrict__ Wt,
                                                      const float* __restrict__ bias,
                                                      half_t* __restrict__ dst) {
  constexpr int KW = NCHUNK * 160 + 8;  // global row stride (968 / 648)
  __shared__ __align__(16) half_t Alds[64 * 168];
  __shared__ __align__(16) half_t Btile[6 * 130 * 24];

  int bid = blockIdx.x;
  int b = bid & 7, strip = bid >> 3;
  int y0 = strip * 4;
  int tid = threadIdx.x;

  int wave = tid >> 6, lane = tid & 63;
  int row = wave >> 1;       // 0..3
  int xh = (wave & 1) * 64;  // x half
  int l15 = lane & 15, q = lane >> 4;

  float4v acc[4][4];
#pragma unroll
  for (int i = 0; i < 4; ++i)
#pragma unroll
    for (int j = 0; j < 4; ++j)
#pragma unroll
      for (int e = 0; e < 4; ++e) acc[i][j][e] = 0.f;

  const half_t* srcb = src + (size_t)b * NH * NW * CIN_PAD;

  for (int chunk = 0; chunk < NCHUNK; ++chunk) {
    __syncthreads();
    // stage A slice: 64 co x 160 k (pad stride 168)
    for (int s = tid; s < 1280; s += 512) {
      int co = s / 20, k8 = s % 20;
      *(half8*)(Alds + co * 168 + k8 * 8) =
          *(const half8*)(Wt + (size_t)co * KW + chunk * 160 + k8 * 8);
    }
    // stage B tile: rows y0-1..y0+4, cols -1..128, 16 ci of this chunk
    for (int s = tid; s < 1560; s += 512) {
      int sub = (s >= 780) ? 1 : 0;
      int s2 = s - sub * 780;
      int trow = s2 / 130, tcol = s2 % 130;
      int yy = y0 - 1 + trow, xx = tcol - 1;
      half8 v;
#pragma unroll
      for (int e = 0; e < 8; ++e) v[e] = (half_t)0.f;
      if (yy >= 0 && yy < NH && xx >= 0 && xx < NW)
        v = *(const half8*)(srcb + ((size_t)yy * NW + xx) * CIN_PAD + chunk * 16 + sub * 8);
      *(half8*)(Btile + ((size_t)trow * 130 + tcol) * 24 + sub * 8) = v;
    }
    __syncthreads();
#pragma unroll
    for (int kk = 0; kk < 5; ++kk) {  // K-step 32 = 2 kykx x 16 ci
      half8 a[4];
#pragma unroll
      for (int mf = 0; mf < 4; ++mf)
        a[mf] = *(const half8*)(Alds + (size_t)(mf * 16 + l15) * 168 + kk * 32 + q * 8);
      int u = q >> 1, cil8 = (q & 1) * 8;
      int kykx = kk * 2 + u;
      int dy = 0, dx = 0;
      if (kykx < 9) { dy = kykx / 3 - 1; dx = kykx % 3 - 1; }  // kykx=9: zero weights
      int trow = row + 1 + dy;
      half8 bf[4];
#pragma unroll
      for (int nf = 0; nf < 4; ++nf) {
        int tcol = 1 + xh + nf * 16 + l15 + dx;
        bf[nf] = *(const half8*)(Btile + ((size_t)trow * 130 + tcol) * 24 + cil8);
      }
#pragma unroll
      for (int mf = 0; mf < 4; ++mf)
#pragma unroll
        for (int nf = 0; nf < 4; ++nf)
          acc[mf][nf] = __builtin_amdgcn_mfma_f32_16x16x32_f16(a[mf], bf[nf], acc[mf][nf], 0, 0, 0);
    }
  }

  // epilogue: D col=l15 (px), row=q*4+e (co); +bias, ReLU, fp16 NHWC store
  int y = y0 + row;
  half_t* dstb = dst + ((size_t)b * NH * NW + (size_t)y * NW) * 64;
#pragma unroll
  for (int mf = 0; mf < 4; ++mf) {
    int cobase = mf * 16 + q * 4;
    float4v bv = *(const float4v*)(bias + cobase);
#pragma unroll
    for (int nf = 0; nf < 4; ++nf) {
      int x = xh + nf * 16 + l15;
      union { half_t h[4]; unsigned long long u64; } pk;
#pragma unroll
      for (int e = 0; e < 4; ++e) {
        float v = acc[mf][nf][e] + bv[e];
        if (RELU) v = v > 0.f ? v : 0.f;
        pk.h[e] = (half_t)v;
      }
      *(unsigned long long*)(dstb + (size_t)x * 64 + cobase) = pk.u64;
    }
  }
}

// ---------------------------------------------------------------------------
// Conv3: 64 -> 2, LDS-staged input tile (swizzled), fp32 NCHW output.
// Block = 2 rows (256 thr). Tile rows y0-1..y0+2, [4][128][64] fp16 swizzled.
// ---------------------------------------------------------------------------
__global__ __launch_bounds__(256) void conv3_kernel(const half_t* __restrict__ h2,
                                                    const half_t* __restrict__ W3t,
                                                    const float* __restrict__ b3,
                                                    float* __restrict__ out) {
  __shared__ __align__(16) half_t w[2 * 576];
  __shared__ __align__(16) half_t tile[4 * 128 * 64];  // 64 KB, swizzled

  int bid = blockIdx.x;
  int b = bid & 7, y0 = (bid >> 3) * 2;
  int tid = threadIdx.x;

  for (int i = tid * 8; i < 1152; i += 256 * 8) *(half8*)(w + i) = *(const half8*)(W3t + i);

  const half_t* hb = h2 + (size_t)b * NH * NW * 64;
  // stage 4 rows: unit = (rr, x, c8): 4096 units, 16/thread
  for (int u = tid; u < 4096; u += 256) {
    int c8 = u & 7, x = (u >> 3) & 127, rr = u >> 10;
    int yy = y0 - 1 + rr;
    half8 v;
#pragma unroll
    for (int e = 0; e < 8; ++e) v[e] = (half_t)0.f;
    if (yy >= 0 && yy < NH) v = *(const half8*)(hb + ((size_t)yy * NW + x) * 64 + c8 * 8);
    int byt = (rr * 16384 + x * 128 + c8 * 16) ^ ((x & 7) << 4);
    *(half8*)((char*)tile + byt) = v;
  }
  __syncthreads();

  int x = tid & 127, ry = tid >> 7;  // ry 0..1
  int y = y0 + ry;
  float a0 = 0.f, a1 = 0.f;
#pragma unroll
  for (int dy = -1; dy <= 1; ++dy) {
#pragma unroll
    for (int dx = -1; dx <= 1; ++dx) {
      int xx = x + dx;
      if (xx < 0 || xx >= NW) continue;
      int kykx = (dy + 1) * 3 + (dx + 1);
      int trow = 1 + ry + dy;
#pragma unroll
      for (int c8 = 0; c8 < 8; ++c8) {
        int byt = (trow * 16384 + xx * 128 + c8 * 16) ^ ((xx & 7) << 4);
        half8 v = *(const half8*)((const char*)tile + byt);
        half8 w0 = *(const half8*)(w + kykx * 64 + c8 * 8);
        half8 w1 = *(const half8*)(w + 576 + kykx * 64 + c8 * 8);
#pragma unroll
        for (int j = 0; j < 8; ++j) {
          a0 = __builtin_fmaf((float)v[j], (float)w0[j], a0);
          a1 = __builtin_fmaf((float)v[j], (float)w1[j], a1);
        }
      }
    }
  }
  out[((size_t)b * 2 + 0) * NH * NW + (size_t)y * NW + x] = a0 + b3[0];
  out[((size_t)b * 2 + 1) * NH * NW + (size_t)y * NW + x] = a1 + b3[1];
}

// ---------------------------------------------------------------------------
extern "C" void kernel_launch(void* const* d_in, const int* in_sizes, int n_in,
                              void* d_out, int out_size, void* d_ws, size_t ws_size,
                              hipStream_t stream) {
  const float* F1 = (const float*)d_in[0];
  const float* F2 = (const float*)d_in[1];
  const float* w1 = (const float*)d_in[2];
  const float* b1 = (const float*)d_in[3];
  const float* w2 = (const float*)d_in[4];
  const float* b2 = (const float*)d_in[5];
  const float* w3 = (const float*)d_in[6];
  const float* b3 = (const float*)d_in[7];
  float* out = (float*)d_out;

  char* ws = (char*)d_ws;
  const size_t corr_bytes = (size_t)NB * NH * NW * CORR_PAD * 2;  // 25165824
  const size_t h_bytes = (size_t)NB * NH * NW * 64 * 2;           // 16777216
  const size_t h1_off = corr_bytes;
  const size_t h2_off = h1_off + h_bytes;
  const size_t wt1_off = h2_off + h_bytes;
  const size_t wt2_off = wt1_off + (size_t)64 * 968 * 2;
  const size_t w3t_off = wt2_off + (size_t)64 * 648 * 2;

  half_t* corr = (half_t*)(ws);
  half_t* h1 = (half_t*)(ws + h1_off);
  half_t* h2 = (half_t*)(ws + h2_off);
  half_t* Wt1 = (half_t*)(ws + wt1_off);
  half_t* Wt2 = (half_t*)(ws + wt2_off);
  half_t* W3t = (half_t*)(ws + w3t_off);

  hipMemsetAsync(corr, 0, corr_bytes, stream);  // zeros ci pad [81,96)
  prep_weights_kernel<<<128, 256, 0, stream>>>(w1, w2, w3, Wt1, Wt2, W3t);
  corr_kernel<<<1024, 512, 0, stream>>>(F1, F2, corr);
  conv_kernel<96, 6, true><<<256, 512, 0, stream>>>(corr, Wt1, b1, h1);
  conv_kernel<64, 4, true><<<256, 512, 0, stream>>>(h1, Wt2, b2, h2);
  conv3_kernel<<<512, 256, 0, stream>>>(h2, W3t, b3, out);
}